// Round 14
// baseline (251.352 us; speedup 1.0000x reference)
//
#include <hip/hip_runtime.h>
#include <hip/hip_bf16.h>
#include <hip/hip_fp16.h>

#define IN_DIM 128
#define HID    64
#define OUT_DIM 40
#define GRP_SH 8                  // 256 nodes per coarse bucket
#define CB_TILE 4096              // edges per coarse block
#define CAP    8000               // region capacity per bucket (max bucket ~4100)

// ---------------- fused: coarse_bin (blocks < nbin) + gemm1 (rest) -----------
// Independent phases overlapped in one dispatch (single-stream serialization fix).
struct SMemG { float Ws[IN_DIM][HID]; float xs[32][IN_DIM]; };  // 48 KB
struct SMemB { int lcnt[512]; int gbase[512]; };                // 4 KB
union  SMemU { SMemG g; SMemB b; };

__global__ __launch_bounds__(256) void bin_gemm1(
        const int* __restrict__ src, const int* __restrict__ dst, int e,
        int nbuk, int nbin, int* __restrict__ ccur, unsigned* __restrict__ pairs,
        const float* __restrict__ x, const float* __restrict__ W1,
        __half* __restrict__ hw1, int n) {
    __shared__ SMemU sm;
    int t = threadIdx.x;
    if ((int)blockIdx.x < nbin) {
        // ---- coarse bin: edges -> packed u32 bucket regions ----
        // packed: (dst & 255) << 24 | src    (src < 2^17)
        for (int i = t; i < nbuk; i += 256) sm.b.lcnt[i] = 0;
        __syncthreads();
        int base = blockIdx.x * CB_TILE;
        int s[16], d[16];
#pragma unroll
        for (int q = 0; q < 16; ++q) {
            int i = base + q * 256 + t;
            if (i < e) { s[q] = src[i]; d[q] = dst[i]; }
            else d[q] = -1;
        }
#pragma unroll
        for (int q = 0; q < 16; ++q)
            if (d[q] >= 0) atomicAdd(&sm.b.lcnt[d[q] >> GRP_SH], 1);
        __syncthreads();
        for (int b = t; b < nbuk; b += 256) {
            int c = sm.b.lcnt[b];
            sm.b.gbase[b] = c ? atomicAdd(&ccur[b], c) : 0;
            sm.b.lcnt[b] = 0;
        }
        __syncthreads();
#pragma unroll
        for (int q = 0; q < 16; ++q) {
            if (d[q] >= 0) {
                int b = d[q] >> GRP_SH;
                int slot = sm.b.gbase[b] + atomicAdd(&sm.b.lcnt[b], 1);
                if (slot < CAP)
                    pairs[(size_t)b * CAP + slot] =
                        ((unsigned)(d[q] & 255) << 24) | (unsigned)s[q];
            }
        }
    } else {
        // ---- gemm1: hw1 = fp16(x @ W1), register-blocked ----
        for (int i = t * 4; i < IN_DIM * HID; i += 256 * 4)
            *(float4*)&sm.g.Ws[0][i] = *(const float4*)&W1[i];
        int base = (blockIdx.x - nbin) * 32;
        for (int i = t; i < 32 * IN_DIM / 4; i += 256) {
            int r = i >> 5, kk = i & 31;
            int gr = base + r;
            float4 v = {0.f, 0.f, 0.f, 0.f};
            if (gr < n) v = *(const float4*)&x[(size_t)gr * IN_DIM + kk * 4];
            *(float4*)&sm.g.xs[r][kk * 4] = v;
        }
        __syncthreads();
        int col = t & 63;
        int rg  = (t >> 6) * 8;
        float acc[8] = {};
#pragma unroll 2
        for (int k = 0; k < IN_DIM; k += 4) {
            float w0 = sm.g.Ws[k + 0][col], w1 = sm.g.Ws[k + 1][col];
            float w2 = sm.g.Ws[k + 2][col], w3 = sm.g.Ws[k + 3][col];
#pragma unroll
            for (int r = 0; r < 8; ++r) {
                float4 xv = *(float4*)&sm.g.xs[rg + r][k];
                acc[r] = fmaf(xv.x, w0, acc[r]);
                acc[r] = fmaf(xv.y, w1, acc[r]);
                acc[r] = fmaf(xv.z, w2, acc[r]);
                acc[r] = fmaf(xv.w, w3, acc[r]);
            }
        }
#pragma unroll
        for (int r = 0; r < 8; ++r) {
            int gr = base + rg + r;
            if (gr < n) hw1[(size_t)gr * HID + col] = __float2half(acc[r]);
        }
    }
}

// ---------------- scan of bucket totals (1 block) ----------------
__global__ void scan_coarse(const int* __restrict__ ccnt, int nbuk, int n,
                            int* __restrict__ cbase, int* __restrict__ off) {
    __shared__ int tmp[512];
    int t = threadIdx.x;
    int v = (t < nbuk) ? ccnt[t] : 0;
    tmp[t] = v;
    __syncthreads();
    for (int ofs = 1; ofs < 512; ofs <<= 1) {
        int a = (t >= ofs) ? tmp[t - ofs] : 0;
        __syncthreads();
        tmp[t] += a;
        __syncthreads();
    }
    if (t < nbuk) cbase[t] = tmp[t] - v;
    if (t == 511) { cbase[nbuk] = tmp[511]; off[n] = tmp[511]; }
}

// ---------------- fine bin: block b owns bucket b entirely --------------------
__global__ __launch_bounds__(256) void fine_bin2(const unsigned* __restrict__ pairs,
                                                 const int* __restrict__ ccnt,
                                                 const int* __restrict__ cbase, int n,
                                                 int* __restrict__ off,
                                                 float* __restrict__ dinv,
                                                 int* __restrict__ sorted) {
    __shared__ int hist[256];
    __shared__ int lpre[256];
    int b = blockIdx.x, t = threadIdx.x;
    int nlo = b << GRP_SH;
    int nnodes = min(256, n - nlo);
    int cnt = min(ccnt[b], CAP);
    const unsigned* reg = pairs + (size_t)b * CAP;
    int gbase = cbase[b];
    hist[t] = 0;
    __syncthreads();
    for (int j = t; j < cnt; j += 256)
        atomicAdd(&hist[reg[j] >> 24], 1);
    __syncthreads();
    int v = hist[t];
    lpre[t] = v;
    __syncthreads();
    for (int ofs = 1; ofs < 256; ofs <<= 1) {
        int a = (t >= ofs) ? lpre[t - ofs] : 0;
        __syncthreads();
        lpre[t] += a;
        __syncthreads();
    }
    int goff = gbase + lpre[t] - v;
    if (t < nnodes) {
        off[nlo + t]  = goff;
        dinv[nlo + t] = rsqrtf((float)v + 1.0f);
    }
    __syncthreads();
    hist[t] = goff;                // reuse as global cursor
    __syncthreads();
    for (int j = t; j < cnt; j += 256) {
        unsigned p = reg[j];
        int pos = atomicAdd(&hist[p >> 24], 1);
        sorted[pos] = (int)(p & 0xFFFFFFu);
    }
}

// ---- gather1: h[d] = fp16(relu(dinv^2*hw1[d] + sum norm*hw1[src] + b1)) -----
// 4 edge-groups x 16 lanes; 4-deep batches: 16 edges in flight per iteration.
__global__ void gather1_h4(const __half* __restrict__ hw1, const float* __restrict__ dinv,
                           const int* __restrict__ off, const int* __restrict__ sorted,
                           const float* __restrict__ b1, __half* __restrict__ hout,
                           int n) {
    int wid  = blockIdx.x * (blockDim.x >> 6) + (threadIdx.x >> 6);
    int lane = threadIdx.x & 63;
    if (wid >= n) return;
    int g = lane >> 4;
    int c = lane & 15;
    float dd = dinv[wid];
    float4 acc = {0.f, 0.f, 0.f, 0.f};
    if (g == 0) {
        uint2 u = *(const uint2*)(hw1 + (size_t)wid * HID + 4 * c);
        __half2 h0 = *(__half2*)&u.x, h1 = *(__half2*)&u.y;
        float s2 = dd * dd;
        acc.x = s2 * __low2float(h0);  acc.y = s2 * __high2float(h0);
        acc.z = s2 * __low2float(h1);  acc.w = s2 * __high2float(h1);
    }
    int j = off[wid], en = off[wid + 1];
    for (; j + 16 <= en; j += 16) {          // 4 batches x 4 edges
        int s0 = sorted[j + g],      s1 = sorted[j + 4 + g];
        int s2i = sorted[j + 8 + g], s3 = sorted[j + 12 + g];
        float w0 = dinv[s0] * dd, w1 = dinv[s1] * dd;
        float w2 = dinv[s2i] * dd, w3 = dinv[s3] * dd;
        uint2 u0 = *(const uint2*)(hw1 + (size_t)s0 * HID + 4 * c);
        uint2 u1 = *(const uint2*)(hw1 + (size_t)s1 * HID + 4 * c);
        uint2 u2 = *(const uint2*)(hw1 + (size_t)s2i * HID + 4 * c);
        uint2 u3 = *(const uint2*)(hw1 + (size_t)s3 * HID + 4 * c);
        __half2 a0 = *(__half2*)&u0.x, a1 = *(__half2*)&u0.y;
        __half2 b0 = *(__half2*)&u1.x, b1h = *(__half2*)&u1.y;
        __half2 c0 = *(__half2*)&u2.x, c1 = *(__half2*)&u2.y;
        __half2 d0 = *(__half2*)&u3.x, d1 = *(__half2*)&u3.y;
        acc.x = fmaf(w0, __low2float(a0), acc.x);
        acc.y = fmaf(w0, __high2float(a0), acc.y);
        acc.z = fmaf(w0, __low2float(a1), acc.z);
        acc.w = fmaf(w0, __high2float(a1), acc.w);
        acc.x = fmaf(w1, __low2float(b0), acc.x);
        acc.y = fmaf(w1, __high2float(b0), acc.y);
        acc.z = fmaf(w1, __low2float(b1h), acc.z);
        acc.w = fmaf(w1, __high2float(b1h), acc.w);
        acc.x = fmaf(w2, __low2float(c0), acc.x);
        acc.y = fmaf(w2, __high2float(c0), acc.y);
        acc.z = fmaf(w2, __low2float(c1), acc.z);
        acc.w = fmaf(w2, __high2float(c1), acc.w);
        acc.x = fmaf(w3, __low2float(d0), acc.x);
        acc.y = fmaf(w3, __high2float(d0), acc.y);
        acc.z = fmaf(w3, __low2float(d1), acc.z);
        acc.w = fmaf(w3, __high2float(d1), acc.w);
    }
    for (; j + 4 <= en; j += 4) {            // 1 batch x 4 edges
        int s = sorted[j + g];
        float w = dinv[s] * dd;
        uint2 u = *(const uint2*)(hw1 + (size_t)s * HID + 4 * c);
        __half2 h0 = *(__half2*)&u.x, h1 = *(__half2*)&u.y;
        acc.x = fmaf(w, __low2float(h0), acc.x);
        acc.y = fmaf(w, __high2float(h0), acc.y);
        acc.z = fmaf(w, __low2float(h1), acc.z);
        acc.w = fmaf(w, __high2float(h1), acc.w);
    }
    int rem = en - j;
    if (g < rem) {
        int s = sorted[j + g];
        float w = dinv[s] * dd;
        uint2 u = *(const uint2*)(hw1 + (size_t)s * HID + 4 * c);
        __half2 h0 = *(__half2*)&u.x, h1 = *(__half2*)&u.y;
        acc.x = fmaf(w, __low2float(h0), acc.x);
        acc.y = fmaf(w, __high2float(h0), acc.y);
        acc.z = fmaf(w, __low2float(h1), acc.z);
        acc.w = fmaf(w, __high2float(h1), acc.w);
    }
    acc.x += __shfl_xor(acc.x, 16); acc.y += __shfl_xor(acc.y, 16);
    acc.z += __shfl_xor(acc.z, 16); acc.w += __shfl_xor(acc.w, 16);
    acc.x += __shfl_xor(acc.x, 32); acc.y += __shfl_xor(acc.y, 32);
    acc.z += __shfl_xor(acc.z, 32); acc.w += __shfl_xor(acc.w, 32);
    if (g == 0) {
        float4 bb = *(const float4*)&b1[4 * c];
        float rx = fmaxf(acc.x + bb.x, 0.f);
        float ry = fmaxf(acc.y + bb.y, 0.f);
        float rz = fmaxf(acc.z + bb.z, 0.f);
        float rw = fmaxf(acc.w + bb.w, 0.f);
        union { __half2 h[2]; uint2 u; } st;
        st.h[0] = __floats2half2_rn(rx, ry);
        st.h[1] = __floats2half2_rn(rz, rw);
        *(uint2*)(hout + (size_t)wid * HID + 4 * c) = st.u;
    }
}

// ---------------- GEMM2: hw2 = fp16(h @ W2) ----------------
__global__ __launch_bounds__(256) void gemm2(const __half* __restrict__ h,
                                             const float* __restrict__ W2,
                                             __half* __restrict__ hw2, int n) {
    __shared__ float Ws[HID][64];
    __shared__ float hs[32][HID];
    int tid = threadIdx.x;
    for (int i = tid; i < HID * 64; i += 256) {
        int k = i >> 6, ccol = i & 63;
        Ws[k][ccol] = (ccol < OUT_DIM) ? W2[k * OUT_DIM + ccol] : 0.f;
    }
    int base = blockIdx.x * 32;
    {
        int r  = tid >> 3;
        int k0 = (tid & 7) * 8;
        int gr = base + r;
        float4 lofl = {0,0,0,0}, hifl = {0,0,0,0};
        if (gr < n) {
            uint4 u = *(const uint4*)(h + (size_t)gr * HID + k0);
            __half2* hp = (__half2*)&u;
            lofl = make_float4(__low2float(hp[0]), __high2float(hp[0]),
                               __low2float(hp[1]), __high2float(hp[1]));
            hifl = make_float4(__low2float(hp[2]), __high2float(hp[2]),
                               __low2float(hp[3]), __high2float(hp[3]));
        }
        *(float4*)&hs[r][k0]     = lofl;
        *(float4*)&hs[r][k0 + 4] = hifl;
    }
    __syncthreads();
    int col = tid & 63;
    int rg  = (tid >> 6) * 8;
    float acc[8] = {};
#pragma unroll 2
    for (int k = 0; k < HID; k += 4) {
        float w0 = Ws[k + 0][col], w1 = Ws[k + 1][col];
        float w2 = Ws[k + 2][col], w3 = Ws[k + 3][col];
#pragma unroll
        for (int r = 0; r < 8; ++r) {
            float4 hv = *(float4*)&hs[rg + r][k];
            acc[r] = fmaf(hv.x, w0, acc[r]);
            acc[r] = fmaf(hv.y, w1, acc[r]);
            acc[r] = fmaf(hv.z, w2, acc[r]);
            acc[r] = fmaf(hv.w, w3, acc[r]);
        }
    }
    if (col < OUT_DIM) {
#pragma unroll
        for (int r = 0; r < 8; ++r) {
            int gr = base + rg + r;
            if (gr < n) hw2[(size_t)gr * OUT_DIM + col] = __float2half(acc[r]);
        }
    }
}

// ---------------- gather2 + finalize: 3 edge-groups x 20 half2 cols -----------
__global__ void gather2_fin(const __half* __restrict__ hw2, const float* __restrict__ dinv,
                            const int* __restrict__ off, const int* __restrict__ sorted,
                            const float* __restrict__ b2, const float* __restrict__ P,
                            const float* __restrict__ Kv, const float* __restrict__ U,
                            float* __restrict__ out, int n) {
    int wid  = blockIdx.x * (blockDim.x >> 6) + (threadIdx.x >> 6);
    int lane = threadIdx.x & 63;
    if (wid >= n) return;
    int g = lane / 20;
    int c = lane % 20;
    bool act = lane < 60;
    float dd = dinv[wid];
    float2 acc = {0.f, 0.f};
    if (lane < 20) {
        __half2 hv = *(const __half2*)(hw2 + (size_t)wid * OUT_DIM + 2 * c);
        acc.x = dd * dd * __low2float(hv);
        acc.y = dd * dd * __high2float(hv);
    }
    int j = off[wid], en = off[wid + 1];
    for (; j + 6 <= en; j += 6) {
        if (act) {
            int sa = sorted[j + g], sb = sorted[j + 3 + g];
            float wa = dinv[sa] * dd, wb = dinv[sb] * dd;
            __half2 va = *(const __half2*)(hw2 + (size_t)sa * OUT_DIM + 2 * c);
            __half2 vb = *(const __half2*)(hw2 + (size_t)sb * OUT_DIM + 2 * c);
            acc.x = fmaf(wa, __low2float(va), acc.x);
            acc.y = fmaf(wa, __high2float(va), acc.y);
            acc.x = fmaf(wb, __low2float(vb), acc.x);
            acc.y = fmaf(wb, __high2float(vb), acc.y);
        }
    }
    for (; j + 3 <= en; j += 3) {
        if (act) {
            int s = sorted[j + g];
            float w = dinv[s] * dd;
            __half2 v = *(const __half2*)(hw2 + (size_t)s * OUT_DIM + 2 * c);
            acc.x = fmaf(w, __low2float(v), acc.x);
            acc.y = fmaf(w, __high2float(v), acc.y);
        }
    }
    int rem = en - j;
    if (act && g < rem) {
        int s = sorted[j + g];
        float w = dinv[s] * dd;
        __half2 v = *(const __half2*)(hw2 + (size_t)s * OUT_DIM + 2 * c);
        acc.x = fmaf(w, __low2float(v), acc.x);
        acc.y = fmaf(w, __high2float(v), acc.y);
    }
    float r1x = __shfl(acc.x, lane + 20), r1y = __shfl(acc.y, lane + 20);
    float r2x = __shfl(acc.x, lane + 40), r2y = __shfl(acc.y, lane + 40);
    float vx = 0.f, vy = 0.f, mym = -INFINITY;
    if (lane < 20) {
        acc.x += r1x + r2x;
        acc.y += r1y + r2y;
        float2 bb = *(const float2*)&b2[2 * c];
        float2 pp = *(const float2*)&P[2 * c];
        float2 kk = *(const float2*)&Kv[2 * c];
        float2 uu = *(const float2*)&U[2 * c];
        vx = fmaxf(acc.x + bb.x + pp.x * kk.x * uu.x, 0.f);
        vy = fmaxf(acc.y + bb.y + pp.y * kk.y * uu.y, 0.f);
        mym = fmaxf(vx, vy);
    }
    float m = mym;
#pragma unroll
    for (int o = 16; o; o >>= 1) m = fmaxf(m, __shfl_xor(m, o));
    float ex = (lane < 20) ? __expf(vx - m) + __expf(vy - m) : 0.f;
    float ssum = ex;
#pragma unroll
    for (int o = 16; o; o >>= 1) ssum += __shfl_xor(ssum, o);
    float lse = m + __logf(ssum);
    if (lane < 20)
        *(float2*)(out + (size_t)wid * OUT_DIM + 2 * c) = make_float2(vx - lse, vy - lse);
}

extern "C" void kernel_launch(void* const* d_in, const int* in_sizes, int n_in,
                              void* d_out, int out_size, void* d_ws, size_t ws_size,
                              hipStream_t stream) {
    const float* x  = (const float*)d_in[0];
    const int*   ei = (const int*)d_in[1];
    const float* W1 = (const float*)d_in[2];
    const float* b1 = (const float*)d_in[3];
    const float* W2 = (const float*)d_in[4];
    const float* b2 = (const float*)d_in[5];
    const float* P  = (const float*)d_in[6];
    const float* K  = (const float*)d_in[7];
    const float* U  = (const float*)d_in[8];
    float* out = (float*)d_out;

    int n = in_sizes[0] / IN_DIM;   // 100000
    int e = in_sizes[1] / 2;        // 1600000
    const int* src = ei;
    const int* dst = ei + e;

    // workspace:
    // ccur[512] | cbase[512] | off[n+1] | dinv[n] | sorted[e]
    //   | (16B) hw1 fp16[n*64] | h fp16[n*64] | hw2 fp16[n*40]
    // pairs u32[nbuk*CAP] (12.5MB) overlays hw1+h (dead before gemm1 writes hw1)
    int*      ccur   = (int*)d_ws;
    int*      cbase  = ccur + 512;
    int*      off    = cbase + 512;
    float*    dinv   = (float*)(off + n + 1);
    int*      sorted = (int*)(dinv + n);
    __half*   hw1    = (__half*)(((uintptr_t)(sorted + e) + 15) & ~(uintptr_t)15);
    __half*   h      = hw1 + (size_t)n * HID;
    __half*   hw2    = h + (size_t)n * HID;
    unsigned* pairs  = (unsigned*)hw1;

    int nbuk = (n + (1 << GRP_SH) - 1) >> GRP_SH;   // 391
    int nbin = (e + CB_TILE - 1) / CB_TILE;          // 391
    int ngemm = (n + 31) / 32;                       // 3125

    // NOTE: pairs overlays hw1 — but coarse_bin writes pairs while gemm1 writes
    // hw1 in the SAME fused kernel. hw1 region starts at the same address as
    // pairs... they must not overlap while both run!  pairs needs
    // nbuk*CAP*4 = 12.5 MB; place pairs AFTER hw2 instead (dead region there).
    unsigned* pairs_safe = (unsigned*)(hw2 + (size_t)n * OUT_DIM);
    pairs = pairs_safe;

    hipMemsetAsync(ccur, 0, 512 * sizeof(int), stream);
    bin_gemm1<<<nbin + ngemm, 256, 0, stream>>>(src, dst, e, nbuk, nbin, ccur, pairs,
                                                x, W1, hw1, n);
    scan_coarse<<<1, 512, 0, stream>>>(ccur, nbuk, n, cbase, off);
    fine_bin2<<<nbuk, 256, 0, stream>>>(pairs, ccur, cbase, n, off, dinv, sorted);

    gather1_h4<<<(n + 3) / 4, 256, 0, stream>>>(hw1, dinv, off, sorted, b1, h, n);
    gemm2<<<(n + 31) / 32, 256, 0, stream>>>(h, W2, hw2, n);
    gather2_fin<<<(n + 3) / 4, 256, 0, stream>>>(hw2, dinv, off, sorted,
                                                 b2, P, K, U, out, n);
}

// Round 16
// 237.480 us; speedup vs baseline: 1.0584x; 1.0584x over previous
//
#include <hip/hip_runtime.h>
#include <hip/hip_bf16.h>
#include <hip/hip_fp16.h>

#define IN_DIM 128
#define HID    64
#define OUT_DIM 40
#define GRP_SH 8                  // 256 nodes per coarse bucket
#define CB_TILE 4096              // edges per coarse block
#define CAP    8000               // region capacity per bucket (max bucket ~4100)

// ---------------- coarse bin: edges -> packed u32 bucket regions --------------
// packed: (dst & 255) << 24 | src    (src < 2^17)
__global__ __launch_bounds__(256) void coarse_bin(const int* __restrict__ src,
                                                  const int* __restrict__ dst, int e,
                                                  int nbuk, int* __restrict__ ccur,
                                                  unsigned* __restrict__ pairs) {
    __shared__ int lcnt[512];
    __shared__ int gbase[512];
    int t = threadIdx.x;
    for (int i = t; i < nbuk; i += 256) lcnt[i] = 0;
    __syncthreads();
    int base = blockIdx.x * CB_TILE;
    int s[16], d[16];
#pragma unroll
    for (int q = 0; q < 16; ++q) {
        int i = base + q * 256 + t;
        if (i < e) { s[q] = src[i]; d[q] = dst[i]; }
        else d[q] = -1;
    }
#pragma unroll
    for (int q = 0; q < 16; ++q)
        if (d[q] >= 0) atomicAdd(&lcnt[d[q] >> GRP_SH], 1);
    __syncthreads();
    for (int b = t; b < nbuk; b += 256) {
        int c = lcnt[b];
        gbase[b] = c ? atomicAdd(&ccur[b], c) : 0;
        lcnt[b] = 0;
    }
    __syncthreads();
#pragma unroll
    for (int q = 0; q < 16; ++q) {
        if (d[q] >= 0) {
            int b = d[q] >> GRP_SH;
            int slot = gbase[b] + atomicAdd(&lcnt[b], 1);
            if (slot < CAP)
                pairs[(size_t)b * CAP + slot] =
                    ((unsigned)(d[q] & 255) << 24) | (unsigned)s[q];
        }
    }
}

// ---------------- fine bin: block b owns bucket b; self-computed prefix -------
// Each block sums ccnt[0..b) itself (<=391 reads + LDS tree) — scan kernel gone.
__global__ __launch_bounds__(256) void fine_bin2(const unsigned* __restrict__ pairs,
                                                 const int* __restrict__ ccnt,
                                                 int nbuk, int n,
                                                 int* __restrict__ off,
                                                 float* __restrict__ dinv,
                                                 int* __restrict__ sorted) {
    __shared__ int red[256];
    __shared__ int hist[256];
    __shared__ int lpre[256];
    int b = blockIdx.x, t = threadIdx.x;
    // prefix sum of bucket counts 0..b-1
    int part = 0;
    for (int i = t; i < b; i += 256) part += ccnt[i];
    red[t] = part;
    __syncthreads();
    for (int ofs = 128; ofs; ofs >>= 1) {
        if (t < ofs) red[t] += red[t + ofs];
        __syncthreads();
    }
    int gbase = red[0];
    int nlo = b << GRP_SH;
    int nnodes = min(256, n - nlo);
    int cnt = min(ccnt[b], CAP);
    if (b == nbuk - 1 && t == 0) off[n] = gbase + cnt;
    const unsigned* reg = pairs + (size_t)b * CAP;
    hist[t] = 0;
    __syncthreads();
    for (int j = t; j < cnt; j += 256)
        atomicAdd(&hist[reg[j] >> 24], 1);
    __syncthreads();
    int v = hist[t];
    lpre[t] = v;
    __syncthreads();
    for (int ofs = 1; ofs < 256; ofs <<= 1) {
        int a = (t >= ofs) ? lpre[t - ofs] : 0;
        __syncthreads();
        lpre[t] += a;
        __syncthreads();
    }
    int goff = gbase + lpre[t] - v;
    if (t < nnodes) {
        off[nlo + t]  = goff;
        dinv[nlo + t] = rsqrtf((float)v + 1.0f);
    }
    __syncthreads();
    hist[t] = goff;                // reuse as global cursor
    __syncthreads();
    for (int j = t; j < cnt; j += 256) {
        unsigned p = reg[j];
        int pos = atomicAdd(&hist[p >> 24], 1);
        sorted[pos] = (int)(p & 0xFFFFFFu);
    }
}

// ---------------- GEMM1: hw1 = fp16(x @ W1), register-blocked ----------------
__global__ __launch_bounds__(256) void gemm1(const float* __restrict__ x,
                                             const float* __restrict__ W1,
                                             __half* __restrict__ hw1, int n) {
    __shared__ float Ws[IN_DIM][HID];    // 32 KB
    __shared__ float xs[32][IN_DIM];     // 16 KB
    int tid = threadIdx.x;
    for (int i = tid * 4; i < IN_DIM * HID; i += 256 * 4)
        *(float4*)&Ws[0][i] = *(const float4*)&W1[i];
    int base = blockIdx.x * 32;
    for (int i = tid; i < 32 * IN_DIM / 4; i += 256) {
        int r = i >> 5, kk = i & 31;
        int gr = base + r;
        float4 v = {0.f, 0.f, 0.f, 0.f};
        if (gr < n) v = *(const float4*)&x[(size_t)gr * IN_DIM + kk * 4];
        *(float4*)&xs[r][kk * 4] = v;
    }
    __syncthreads();
    int col = tid & 63;
    int rg  = (tid >> 6) * 8;
    float acc[8] = {};
#pragma unroll 2
    for (int k = 0; k < IN_DIM; k += 4) {
        float w0 = Ws[k + 0][col], w1 = Ws[k + 1][col];
        float w2 = Ws[k + 2][col], w3 = Ws[k + 3][col];
#pragma unroll
        for (int r = 0; r < 8; ++r) {
            float4 xv = *(float4*)&xs[rg + r][k];
            acc[r] = fmaf(xv.x, w0, acc[r]);
            acc[r] = fmaf(xv.y, w1, acc[r]);
            acc[r] = fmaf(xv.z, w2, acc[r]);
            acc[r] = fmaf(xv.w, w3, acc[r]);
        }
    }
#pragma unroll
    for (int r = 0; r < 8; ++r) {
        int gr = base + rg + r;
        if (gr < n) hw1[(size_t)gr * HID + col] = __float2half(acc[r]);
    }
}

// ---- gather1: h[d] = fp16(relu(dinv^2*hw1[d] + sum norm*hw1[src] + b1)) -----
// 4 edge-groups x 16 lanes; 4-deep batches: 16 edges in flight per iteration.
__global__ void gather1_h4(const __half* __restrict__ hw1, const float* __restrict__ dinv,
                           const int* __restrict__ off, const int* __restrict__ sorted,
                           const float* __restrict__ b1, __half* __restrict__ hout,
                           int n) {
    int wid  = blockIdx.x * (blockDim.x >> 6) + (threadIdx.x >> 6);
    int lane = threadIdx.x & 63;
    if (wid >= n) return;
    int g = lane >> 4;
    int c = lane & 15;
    float dd = dinv[wid];
    float4 acc = {0.f, 0.f, 0.f, 0.f};
    if (g == 0) {
        uint2 u = *(const uint2*)(hw1 + (size_t)wid * HID + 4 * c);
        __half2 h0 = *(__half2*)&u.x, h1 = *(__half2*)&u.y;
        float s2 = dd * dd;
        acc.x = s2 * __low2float(h0);  acc.y = s2 * __high2float(h0);
        acc.z = s2 * __low2float(h1);  acc.w = s2 * __high2float(h1);
    }
    int j = off[wid], en = off[wid + 1];
    for (; j + 16 <= en; j += 16) {          // 4 batches x 4 edges
        int s0 = sorted[j + g],      s1 = sorted[j + 4 + g];
        int s2i = sorted[j + 8 + g], s3 = sorted[j + 12 + g];
        float w0 = dinv[s0] * dd, w1 = dinv[s1] * dd;
        float w2 = dinv[s2i] * dd, w3 = dinv[s3] * dd;
        uint2 u0 = *(const uint2*)(hw1 + (size_t)s0 * HID + 4 * c);
        uint2 u1 = *(const uint2*)(hw1 + (size_t)s1 * HID + 4 * c);
        uint2 u2 = *(const uint2*)(hw1 + (size_t)s2i * HID + 4 * c);
        uint2 u3 = *(const uint2*)(hw1 + (size_t)s3 * HID + 4 * c);
        __half2 a0 = *(__half2*)&u0.x, a1 = *(__half2*)&u0.y;
        __half2 b0 = *(__half2*)&u1.x, b1h = *(__half2*)&u1.y;
        __half2 c0 = *(__half2*)&u2.x, c1 = *(__half2*)&u2.y;
        __half2 d0 = *(__half2*)&u3.x, d1 = *(__half2*)&u3.y;
        acc.x = fmaf(w0, __low2float(a0), acc.x);
        acc.y = fmaf(w0, __high2float(a0), acc.y);
        acc.z = fmaf(w0, __low2float(a1), acc.z);
        acc.w = fmaf(w0, __high2float(a1), acc.w);
        acc.x = fmaf(w1, __low2float(b0), acc.x);
        acc.y = fmaf(w1, __high2float(b0), acc.y);
        acc.z = fmaf(w1, __low2float(b1h), acc.z);
        acc.w = fmaf(w1, __high2float(b1h), acc.w);
        acc.x = fmaf(w2, __low2float(c0), acc.x);
        acc.y = fmaf(w2, __high2float(c0), acc.y);
        acc.z = fmaf(w2, __low2float(c1), acc.z);
        acc.w = fmaf(w2, __high2float(c1), acc.w);
        acc.x = fmaf(w3, __low2float(d0), acc.x);
        acc.y = fmaf(w3, __high2float(d0), acc.y);
        acc.z = fmaf(w3, __low2float(d1), acc.z);
        acc.w = fmaf(w3, __high2float(d1), acc.w);
    }
    for (; j + 4 <= en; j += 4) {            // 1 batch x 4 edges
        int s = sorted[j + g];
        float w = dinv[s] * dd;
        uint2 u = *(const uint2*)(hw1 + (size_t)s * HID + 4 * c);
        __half2 h0 = *(__half2*)&u.x, h1 = *(__half2*)&u.y;
        acc.x = fmaf(w, __low2float(h0), acc.x);
        acc.y = fmaf(w, __high2float(h0), acc.y);
        acc.z = fmaf(w, __low2float(h1), acc.z);
        acc.w = fmaf(w, __high2float(h1), acc.w);
    }
    int rem = en - j;
    if (g < rem) {
        int s = sorted[j + g];
        float w = dinv[s] * dd;
        uint2 u = *(const uint2*)(hw1 + (size_t)s * HID + 4 * c);
        __half2 h0 = *(__half2*)&u.x, h1 = *(__half2*)&u.y;
        acc.x = fmaf(w, __low2float(h0), acc.x);
        acc.y = fmaf(w, __high2float(h0), acc.y);
        acc.z = fmaf(w, __low2float(h1), acc.z);
        acc.w = fmaf(w, __high2float(h1), acc.w);
    }
    acc.x += __shfl_xor(acc.x, 16); acc.y += __shfl_xor(acc.y, 16);
    acc.z += __shfl_xor(acc.z, 16); acc.w += __shfl_xor(acc.w, 16);
    acc.x += __shfl_xor(acc.x, 32); acc.y += __shfl_xor(acc.y, 32);
    acc.z += __shfl_xor(acc.z, 32); acc.w += __shfl_xor(acc.w, 32);
    if (g == 0) {
        float4 bb = *(const float4*)&b1[4 * c];
        float rx = fmaxf(acc.x + bb.x, 0.f);
        float ry = fmaxf(acc.y + bb.y, 0.f);
        float rz = fmaxf(acc.z + bb.z, 0.f);
        float rw = fmaxf(acc.w + bb.w, 0.f);
        union { __half2 h[2]; uint2 u; } st;
        st.h[0] = __floats2half2_rn(rx, ry);
        st.h[1] = __floats2half2_rn(rz, rw);
        *(uint2*)(hout + (size_t)wid * HID + 4 * c) = st.u;
    }
}

// ---------------- GEMM2: hw2 = fp16(h @ W2) ----------------
__global__ __launch_bounds__(256) void gemm2(const __half* __restrict__ h,
                                             const float* __restrict__ W2,
                                             __half* __restrict__ hw2, int n) {
    __shared__ float Ws[HID][64];
    __shared__ float hs[32][HID];
    int tid = threadIdx.x;
    for (int i = tid; i < HID * 64; i += 256) {
        int k = i >> 6, ccol = i & 63;
        Ws[k][ccol] = (ccol < OUT_DIM) ? W2[k * OUT_DIM + ccol] : 0.f;
    }
    int base = blockIdx.x * 32;
    {
        int r  = tid >> 3;
        int k0 = (tid & 7) * 8;
        int gr = base + r;
        float4 lofl = {0,0,0,0}, hifl = {0,0,0,0};
        if (gr < n) {
            uint4 u = *(const uint4*)(h + (size_t)gr * HID + k0);
            __half2* hp = (__half2*)&u;
            lofl = make_float4(__low2float(hp[0]), __high2float(hp[0]),
                               __low2float(hp[1]), __high2float(hp[1]));
            hifl = make_float4(__low2float(hp[2]), __high2float(hp[2]),
                               __low2float(hp[3]), __high2float(hp[3]));
        }
        *(float4*)&hs[r][k0]     = lofl;
        *(float4*)&hs[r][k0 + 4] = hifl;
    }
    __syncthreads();
    int col = tid & 63;
    int rg  = (tid >> 6) * 8;
    float acc[8] = {};
#pragma unroll 2
    for (int k = 0; k < HID; k += 4) {
        float w0 = Ws[k + 0][col], w1 = Ws[k + 1][col];
        float w2 = Ws[k + 2][col], w3 = Ws[k + 3][col];
#pragma unroll
        for (int r = 0; r < 8; ++r) {
            float4 hv = *(float4*)&hs[rg + r][k];
            acc[r] = fmaf(hv.x, w0, acc[r]);
            acc[r] = fmaf(hv.y, w1, acc[r]);
            acc[r] = fmaf(hv.z, w2, acc[r]);
            acc[r] = fmaf(hv.w, w3, acc[r]);
        }
    }
    if (col < OUT_DIM) {
#pragma unroll
        for (int r = 0; r < 8; ++r) {
            int gr = base + rg + r;
            if (gr < n) hw2[(size_t)gr * OUT_DIM + col] = __float2half(acc[r]);
        }
    }
}

// ---------------- gather2 + finalize: 3 edge-groups x 20 half2 cols -----------
__global__ void gather2_fin(const __half* __restrict__ hw2, const float* __restrict__ dinv,
                            const int* __restrict__ off, const int* __restrict__ sorted,
                            const float* __restrict__ b2, const float* __restrict__ P,
                            const float* __restrict__ Kv, const float* __restrict__ U,
                            float* __restrict__ out, int n) {
    int wid  = blockIdx.x * (blockDim.x >> 6) + (threadIdx.x >> 6);
    int lane = threadIdx.x & 63;
    if (wid >= n) return;
    int g = lane / 20;
    int c = lane % 20;
    bool act = lane < 60;
    float dd = dinv[wid];
    float2 acc = {0.f, 0.f};
    if (lane < 20) {
        __half2 hv = *(const __half2*)(hw2 + (size_t)wid * OUT_DIM + 2 * c);
        acc.x = dd * dd * __low2float(hv);
        acc.y = dd * dd * __high2float(hv);
    }
    int j = off[wid], en = off[wid + 1];
    for (; j + 6 <= en; j += 6) {
        if (act) {
            int sa = sorted[j + g], sb = sorted[j + 3 + g];
            float wa = dinv[sa] * dd, wb = dinv[sb] * dd;
            __half2 va = *(const __half2*)(hw2 + (size_t)sa * OUT_DIM + 2 * c);
            __half2 vb = *(const __half2*)(hw2 + (size_t)sb * OUT_DIM + 2 * c);
            acc.x = fmaf(wa, __low2float(va), acc.x);
            acc.y = fmaf(wa, __high2float(va), acc.y);
            acc.x = fmaf(wb, __low2float(vb), acc.x);
            acc.y = fmaf(wb, __high2float(vb), acc.y);
        }
    }
    for (; j + 3 <= en; j += 3) {
        if (act) {
            int s = sorted[j + g];
            float w = dinv[s] * dd;
            __half2 v = *(const __half2*)(hw2 + (size_t)s * OUT_DIM + 2 * c);
            acc.x = fmaf(w, __low2float(v), acc.x);
            acc.y = fmaf(w, __high2float(v), acc.y);
        }
    }
    int rem = en - j;
    if (act && g < rem) {
        int s = sorted[j + g];
        float w = dinv[s] * dd;
        __half2 v = *(const __half2*)(hw2 + (size_t)s * OUT_DIM + 2 * c);
        acc.x = fmaf(w, __low2float(v), acc.x);
        acc.y = fmaf(w, __high2float(v), acc.y);
    }
    float r1x = __shfl(acc.x, lane + 20), r1y = __shfl(acc.y, lane + 20);
    float r2x = __shfl(acc.x, lane + 40), r2y = __shfl(acc.y, lane + 40);
    float vx = 0.f, vy = 0.f, mym = -INFINITY;
    if (lane < 20) {
        acc.x += r1x + r2x;
        acc.y += r1y + r2y;
        float2 bb = *(const float2*)&b2[2 * c];
        float2 pp = *(const float2*)&P[2 * c];
        float2 kk = *(const float2*)&Kv[2 * c];
        float2 uu = *(const float2*)&U[2 * c];
        vx = fmaxf(acc.x + bb.x + pp.x * kk.x * uu.x, 0.f);
        vy = fmaxf(acc.y + bb.y + pp.y * kk.y * uu.y, 0.f);
        mym = fmaxf(vx, vy);
    }
    float m = mym;
#pragma unroll
    for (int o = 16; o; o >>= 1) m = fmaxf(m, __shfl_xor(m, o));
    float ex = (lane < 20) ? __expf(vx - m) + __expf(vy - m) : 0.f;
    float ssum = ex;
#pragma unroll
    for (int o = 16; o; o >>= 1) ssum += __shfl_xor(ssum, o);
    float lse = m + __logf(ssum);
    if (lane < 20)
        *(float2*)(out + (size_t)wid * OUT_DIM + 2 * c) = make_float2(vx - lse, vy - lse);
}

extern "C" void kernel_launch(void* const* d_in, const int* in_sizes, int n_in,
                              void* d_out, int out_size, void* d_ws, size_t ws_size,
                              hipStream_t stream) {
    const float* x  = (const float*)d_in[0];
    const int*   ei = (const int*)d_in[1];
    const float* W1 = (const float*)d_in[2];
    const float* b1 = (const float*)d_in[3];
    const float* W2 = (const float*)d_in[4];
    const float* b2 = (const float*)d_in[5];
    const float* P  = (const float*)d_in[6];
    const float* K  = (const float*)d_in[7];
    const float* U  = (const float*)d_in[8];
    float* out = (float*)d_out;

    int n = in_sizes[0] / IN_DIM;   // 100000
    int e = in_sizes[1] / 2;        // 1600000
    const int* src = ei;
    const int* dst = ei + e;

    // workspace:
    // ccur[512] | off[n+1] | dinv[n] | sorted[e]
    //   | (16B) hw1 fp16[n*64] | h fp16[n*64] | hw2 fp16[n*40]
    // pairs u32[nbuk*CAP] (12.5MB) overlays hw1+h (dead before gemm1 writes hw1)
    int*      ccur   = (int*)d_ws;
    int*      off    = ccur + 512;
    float*    dinv   = (float*)(off + n + 1);
    int*      sorted = (int*)(dinv + n);
    __half*   hw1    = (__half*)(((uintptr_t)(sorted + e) + 15) & ~(uintptr_t)15);
    __half*   h      = hw1 + (size_t)n * HID;
    __half*   hw2    = h + (size_t)n * HID;
    unsigned* pairs  = (unsigned*)hw1;

    int nbuk = (n + (1 << GRP_SH) - 1) >> GRP_SH;   // 391

    hipMemsetAsync(ccur, 0, 512 * sizeof(int), stream);
    coarse_bin<<<(e + CB_TILE - 1) / CB_TILE, 256, 0, stream>>>(src, dst, e, nbuk,
                                                                ccur, pairs);
    fine_bin2<<<nbuk, 256, 0, stream>>>(pairs, ccur, nbuk, n, off, dinv, sorted);

    gemm1<<<(n + 31) / 32, 256, 0, stream>>>(x, W1, hw1, n);
    gather1_h4<<<(n + 3) / 4, 256, 0, stream>>>(hw1, dinv, off, sorted, b1, h, n);
    gemm2<<<(n + 31) / 32, 256, 0, stream>>>(h, W2, hw2, n);
    gather2_fin<<<(n + 3) / 4, 256, 0, stream>>>(hw2, dinv, off, sorted,
                                                 b2, P, K, U, out, n);
}